// Round 1
// baseline (136.711 us; speedup 1.0000x reference)
//
#include <hip/hip_runtime.h>
#include <hip/hip_bf16.h>

// out[e] = W2 . relu( u[row[e]] + v[col[e]] ) + b2
// where u[n] = Wu.seq[n] + bu,  v[n] = Wv.seq[n] + bv
//   Wu = W1[:, :64] @ W_enc   (64x128), bu = W1[:, :64] @ b_enc + b1
//   Wv = W1[:, 64:] @ W_enc   (64x128), bv = W1[:, 64:] @ b_enc
// UV table stores [u | v] per node: [N_NODES][128] f32.
// W_t stored transposed [k][out] so inner GEMM reads are wave-uniform (s_load).

#define N_OUT 128   // 64 u + 64 v
#define K_IN  128

__global__ __launch_bounds__(256) void prep_kernel(
        const float* __restrict__ W_enc, const float* __restrict__ b_enc,
        const float* __restrict__ W1,    const float* __restrict__ b1,
        float* __restrict__ Wt, float* __restrict__ bcat)
{
    int idx = blockIdx.x * blockDim.x + threadIdx.x;   // 0..16383
    if (idx >= K_IN * N_OUT) return;
    int k = idx >> 7;        // 0..127 (input dim)
    int i = idx & 127;       // 0..127 (output dim: 0..63 = u, 64..127 = v)
    int irow = (i < 64) ? i : (i - 64);
    int joff = (i < 64) ? 0 : 64;
    float s = 0.f;
    #pragma unroll 8
    for (int j = 0; j < 64; ++j)
        s = fmaf(W1[irow * 128 + joff + j], W_enc[j * 128 + k], s);
    Wt[k * N_OUT + i] = s;
    if (k == 0) {
        float b = 0.f;
        for (int j = 0; j < 64; ++j)
            b = fmaf(W1[irow * 128 + joff + j], b_enc[j], b);
        if (i < 64) b += b1[i];
        bcat[i] = b;
    }
}

// One node per lane; 4 waves per block each cover a 32-wide output chunk.
// W reads are wave-uniform -> scalar loads; seq rows (64 per block, 32 KB)
// stay L1-resident across the 4 waves.
__global__ __launch_bounds__(256) void node_proj_kernel(
        const float* __restrict__ seq, const float* __restrict__ Wt,
        const float* __restrict__ bcat, float* __restrict__ UV, int nNodes)
{
    int lane = threadIdx.x & 63;
    int c = __builtin_amdgcn_readfirstlane((int)(threadIdx.x >> 6)); // 0..3
    int node = blockIdx.x * 64 + lane;
    if (node >= nNodes) return;

    const float4* srow = (const float4*)(seq + (size_t)node * K_IN);

    float acc[32];
    #pragma unroll
    for (int j = 0; j < 32; ++j) acc[j] = bcat[c * 32 + j];

    #pragma unroll 2
    for (int k4 = 0; k4 < K_IN / 4; ++k4) {
        float4 s = srow[k4];
        #pragma unroll
        for (int kk = 0; kk < 4; ++kk) {
            float sv = (kk == 0) ? s.x : (kk == 1) ? s.y : (kk == 2) ? s.z : s.w;
            const float* wrow = Wt + (k4 * 4 + kk) * N_OUT + c * 32;
            #pragma unroll
            for (int j = 0; j < 32; ++j)
                acc[j] = fmaf(wrow[j], sv, acc[j]);
        }
    }

    float* orow = UV + (size_t)node * N_OUT + c * 32;
    #pragma unroll
    for (int j = 0; j < 32; j += 4) {
        float4 o = make_float4(acc[j], acc[j + 1], acc[j + 2], acc[j + 3]);
        *(float4*)(orow + j) = o;
    }
}

// 16 lanes per edge, each lane handles 4 of 64 hidden units via float4.
__global__ __launch_bounds__(256) void edge_kernel(
        const float* __restrict__ UV, const int* __restrict__ row,
        const int* __restrict__ col, const float* __restrict__ W2,
        const float* __restrict__ b2, float* __restrict__ out, int nEdges)
{
    int l = threadIdx.x & 15;
    float4 w2 = *(const float4*)(W2 + l * 4);
    float bb = b2[0];

    int gid = (int)((blockIdx.x * blockDim.x + threadIdx.x) >> 4);
    int ngroups = (int)((gridDim.x * blockDim.x) >> 4);

    for (int e = gid; e < nEdges; e += ngroups) {
        int r = row[e];
        int cc = col[e];
        const float4* up = (const float4*)(UV + (size_t)r * N_OUT);
        const float4* vp = (const float4*)(UV + (size_t)cc * N_OUT + 64);
        float4 a = up[l];
        float4 b = vp[l];
        float h0 = fmaxf(a.x + b.x, 0.f);
        float h1 = fmaxf(a.y + b.y, 0.f);
        float h2 = fmaxf(a.z + b.z, 0.f);
        float h3 = fmaxf(a.w + b.w, 0.f);
        float p = fmaf(h0, w2.x, fmaf(h1, w2.y, fmaf(h2, w2.z, h3 * w2.w)));
        p += __shfl_xor(p, 1);
        p += __shfl_xor(p, 2);
        p += __shfl_xor(p, 4);
        p += __shfl_xor(p, 8);
        if (l == 0) out[e] = p + bb;
    }
}

extern "C" void kernel_launch(void* const* d_in, const int* in_sizes, int n_in,
                              void* d_out, int out_size, void* d_ws, size_t ws_size,
                              hipStream_t stream) {
    const float* seq   = (const float*)d_in[0];
    const float* W_enc = (const float*)d_in[1];
    const float* b_enc = (const float*)d_in[2];
    const float* W1    = (const float*)d_in[3];
    const float* b1    = (const float*)d_in[4];
    const float* W2    = (const float*)d_in[5];
    const float* b2    = (const float*)d_in[6];
    const int*   row   = (const int*)d_in[7];
    const int*   col   = (const int*)d_in[8];
    float* out = (float*)d_out;

    int nNodes = in_sizes[0] / K_IN;     // 100000
    int nEdges = in_sizes[7];            // 1000000

    // workspace layout
    float* UV   = (float*)d_ws;                                 // nNodes*128 f32
    float* Wt   = (float*)((char*)d_ws + (size_t)nNodes * N_OUT * sizeof(float));
    float* bcat = Wt + K_IN * N_OUT;

    // 1) fold weights
    prep_kernel<<<(K_IN * N_OUT + 255) / 256, 256, 0, stream>>>(
        W_enc, b_enc, W1, b1, Wt, bcat);

    // 2) per-node projections  UV = seq @ Wt + bcat
    int nblocksA = (nNodes + 63) / 64;
    node_proj_kernel<<<nblocksA, 256, 0, stream>>>(seq, Wt, bcat, UV, nNodes);

    // 3) per-edge gather + relu + dot
    edge_kernel<<<4096, 256, 0, stream>>>(UV, row, col, W2, b2, out, nEdges);
}

// Round 2
// 60.017 us; speedup vs baseline: 2.2779x; 2.2779x over previous
//
#include <hip/hip_runtime.h>
#include <hip/hip_bf16.h>

// out[e] = W2 . relu( u[row[e]] + v[col[e]] ) + b2
//   u[n] = (W1a@W_enc).seq[n] + (W1a.b_enc + b1)
//   v[n] = (W1b@W_enc).seq[n] +  W1b.b_enc
// UV table: [N_NODES][128] _Float16  (64 u | 64 v).
// Folded weight Wb: [128 out][128 k] bf16 (for MFMA B-operand reads).

#define K_IN  128
#define N_OUT 128
#define LDA   136   // 128 + 8 bf16 pad (row stride 272 B, breaks bank phase)
#define LDB   136

typedef short bf16x8 __attribute__((ext_vector_type(8)));
typedef float f32x4  __attribute__((ext_vector_type(4)));
typedef _Float16 half8 __attribute__((ext_vector_type(8)));

static __device__ __forceinline__ short f2bf(float x) {
    __hip_bfloat16 h = __float2bfloat16(x);
    return *reinterpret_cast<short*>(&h);
}

// ---------------- prep: fold weights into Wb[out][k] bf16 + bias ----------
__global__ __launch_bounds__(256) void prep_kernel(
        const float* __restrict__ W_enc, const float* __restrict__ b_enc,
        const float* __restrict__ W1,    const float* __restrict__ b1,
        __hip_bfloat16* __restrict__ Wb, float* __restrict__ bcat)
{
    int idx = blockIdx.x * blockDim.x + threadIdx.x;   // 0..16383
    if (idx >= N_OUT * K_IN) return;
    int i = idx >> 7;        // out 0..127 (0..63 = u, 64..127 = v)
    int k = idx & 127;       // in  0..127
    int irow = i & 63;
    int joff = (i < 64) ? 0 : 64;
    float s = 0.f;
    #pragma unroll 8
    for (int j = 0; j < 64; ++j)
        s = fmaf(W1[irow * 128 + joff + j], W_enc[j * 128 + k], s);
    Wb[i * K_IN + k] = __float2bfloat16(s);
    if (k == 0) {
        float b = 0.f;
        for (int j = 0; j < 64; ++j)
            b = fmaf(W1[irow * 128 + joff + j], b_enc[j], b);
        if (i < 64) b += b1[i];
        bcat[i] = b;
    }
}

// ---------------- node projection: UVh = bf16MFMA(seq, Wb) + bcat ---------
// block = 256 threads (4 waves), 64 nodes x 128 outputs, K = 128.
__global__ __launch_bounds__(256) void node_proj_kernel(
        const float* __restrict__ seq, const __hip_bfloat16* __restrict__ Wb,
        const float* __restrict__ bcat, _Float16* __restrict__ UVh, int nNodes)
{
    __shared__ short As[64 * LDA];
    __shared__ short Bs[N_OUT * LDB];

    int tid  = threadIdx.x;
    int base = blockIdx.x * 64;

    // stage A: 64 rows x 128 cols fp32 -> bf16 LDS (coalesced float4 loads)
    #pragma unroll
    for (int it = 0; it < 8; ++it) {
        int f4 = tid + 256 * it;            // float4 index 0..2047
        int r  = f4 >> 5;                   // node row 0..63
        int cb = (f4 & 31) * 4;             // col 0..124
        int node = base + r;
        if (node >= nNodes) node = nNodes - 1;
        float4 s = *(const float4*)(seq + (size_t)node * K_IN + cb);
        short4 p;
        p.x = f2bf(s.x); p.y = f2bf(s.y); p.z = f2bf(s.z); p.w = f2bf(s.w);
        *(short4*)(As + r * LDA + cb) = p;
    }
    // stage B: Wb [128][128] bf16 -> LDS (16B chunks, coalesced)
    #pragma unroll
    for (int it = 0; it < 8; ++it) {
        int c8 = tid + 256 * it;            // 8-elem chunk 0..2047
        int r  = c8 >> 4;                   // out row 0..127
        int cb = (c8 & 15) * 8;             // k 0..120
        int4 w = *(const int4*)(Wb + r * K_IN + cb);
        *(int4*)(Bs + r * LDB + cb) = w;
    }
    __syncthreads();

    int lane = tid & 63;
    int w    = tid >> 6;       // wave 0..3 -> rows [16w, 16w+16)
    int lr   = lane & 15;
    int lg   = lane >> 4;

    f32x4 acc[8];
    #pragma unroll
    for (int nt = 0; nt < 8; ++nt) {
        float b = bcat[nt * 16 + lr];
        acc[nt] = (f32x4){b, b, b, b};
    }

    #pragma unroll
    for (int kk = 0; kk < 4; ++kk) {
        bf16x8 a = *(bf16x8*)(As + (16 * w + lr) * LDA + kk * 32 + lg * 8);
        #pragma unroll
        for (int nt = 0; nt < 8; ++nt) {
            bf16x8 b = *(bf16x8*)(Bs + (nt * 16 + lr) * LDB + kk * 32 + lg * 8);
            acc[nt] = __builtin_amdgcn_mfma_f32_16x16x32_bf16(a, b, acc[nt], 0, 0, 0);
        }
    }

    // store: D col = lane&15 (+16*nt), row = 4*lg + j  (m89/m91 mapping)
    int nodeb = base + 16 * w + lg * 4;
    #pragma unroll
    for (int j = 0; j < 4; ++j) {
        int node = nodeb + j;
        if (node < nNodes) {
            #pragma unroll
            for (int nt = 0; nt < 8; ++nt)
                UVh[(size_t)node * N_OUT + nt * 16 + lr] = (_Float16)acc[nt][j];
        }
    }
}

// ---------------- edge: 8 lanes/edge, fp16 gathers (16 B/lane/row) --------
__global__ __launch_bounds__(256) void edge_kernel(
        const _Float16* __restrict__ UVh, const int* __restrict__ row,
        const int* __restrict__ col, const float* __restrict__ W2,
        const float* __restrict__ b2, float* __restrict__ out, int nEdges)
{
    int l = threadIdx.x & 7;
    float w2v[8];
    #pragma unroll
    for (int j = 0; j < 8; ++j) w2v[j] = W2[l * 8 + j];
    float bb = b2[0];

    int gid = (int)((blockIdx.x * blockDim.x + threadIdx.x) >> 3);
    int ng  = (int)((gridDim.x * blockDim.x) >> 3);

    for (int e = gid; e < nEdges; e += ng) {
        int r = row[e];
        int c = col[e];
        half8 a = *(const half8*)(UVh + (size_t)r * N_OUT + l * 8);
        half8 b = *(const half8*)(UVh + (size_t)c * N_OUT + 64 + l * 8);
        float p = 0.f;
        #pragma unroll
        for (int j = 0; j < 8; ++j) {
            float h = (float)a[j] + (float)b[j];
            h = fmaxf(h, 0.f);
            p = fmaf(h, w2v[j], p);
        }
        p += __shfl_xor(p, 1);
        p += __shfl_xor(p, 2);
        p += __shfl_xor(p, 4);
        if (l == 0) out[e] = p + bb;
    }
}

extern "C" void kernel_launch(void* const* d_in, const int* in_sizes, int n_in,
                              void* d_out, int out_size, void* d_ws, size_t ws_size,
                              hipStream_t stream) {
    const float* seq   = (const float*)d_in[0];
    const float* W_enc = (const float*)d_in[1];
    const float* b_enc = (const float*)d_in[2];
    const float* W1    = (const float*)d_in[3];
    const float* b1    = (const float*)d_in[4];
    const float* W2    = (const float*)d_in[5];
    const float* b2    = (const float*)d_in[6];
    const int*   row   = (const int*)d_in[7];
    const int*   col   = (const int*)d_in[8];
    float* out = (float*)d_out;

    int nNodes = in_sizes[0] / K_IN;     // 100000
    int nEdges = in_sizes[7];            // 1000000

    // workspace layout
    _Float16* UVh = (_Float16*)d_ws;                                   // 25.6 MB
    __hip_bfloat16* Wb = (__hip_bfloat16*)((char*)d_ws +
                         (size_t)nNodes * N_OUT * sizeof(_Float16));   // 32 KB
    float* bcat = (float*)((char*)Wb + N_OUT * K_IN * sizeof(__hip_bfloat16));

    prep_kernel<<<(N_OUT * K_IN + 255) / 256, 256, 0, stream>>>(
        W_enc, b_enc, W1, b1, Wb, bcat);

    int nblocksA = (nNodes + 63) / 64;
    node_proj_kernel<<<nblocksA, 256, 0, stream>>>(seq, Wb, bcat, UVh, nNodes);

    edge_kernel<<<2048, 256, 0, stream>>>(UVh, row, col, W2, b2, out, nEdges);
}

// Round 3
// 59.851 us; speedup vs baseline: 2.2842x; 1.0028x over previous
//
#include <hip/hip_runtime.h>
#include <hip/hip_bf16.h>

// out[e] = W2 . relu( u[row[e]] + v[col[e]] ) + b2
//   u[n] = (W1a@W_enc).seq[n] + (W1a.b_enc + b1)
//   v[n] = (W1b@W_enc).seq[n] +  W1b.b_enc
// UV table: [N_NODES][128] _Float16  (64 u | 64 v).
// Folded weight Wb: [128 out][128 k] bf16 (MFMA B operand).

#define K_IN  128
#define N_OUT 128
#define LDB   136   // 128 + 8 bf16 pad (row stride 272 B -> ~2-way banks, free)

typedef short bf16x8 __attribute__((ext_vector_type(8)));
typedef float f32x4  __attribute__((ext_vector_type(4)));
typedef _Float16 half8 __attribute__((ext_vector_type(8)));

static __device__ __forceinline__ short f2bf(float x) {
    __hip_bfloat16 h = __float2bfloat16(x);
    return *reinterpret_cast<short*>(&h);
}

// ---------------- prep: fold weights into Wb[out][k] bf16 + bias ----------
__global__ __launch_bounds__(256) void prep_kernel(
        const float* __restrict__ W_enc, const float* __restrict__ b_enc,
        const float* __restrict__ W1,    const float* __restrict__ b1,
        __hip_bfloat16* __restrict__ Wb, float* __restrict__ bcat)
{
    int idx = blockIdx.x * blockDim.x + threadIdx.x;   // 0..16383
    if (idx >= N_OUT * K_IN) return;
    int i = idx >> 7;        // out 0..127 (0..63 = u, 64..127 = v)
    int k = idx & 127;       // in  0..127
    int irow = i & 63;
    int joff = (i < 64) ? 0 : 64;
    float s = 0.f;
    #pragma unroll 8
    for (int j = 0; j < 64; ++j)
        s = fmaf(W1[irow * 128 + joff + j], W_enc[j * 128 + k], s);
    Wb[i * K_IN + k] = __float2bfloat16(s);
    if (k == 0) {
        float b = 0.f;
        for (int j = 0; j < 64; ++j)
            b = fmaf(W1[irow * 128 + joff + j], b_enc[j], b);
        if (i < 64) b += b1[i];
        bcat[i] = b;
    }
}

// ---------------- node projection: UVh = bf16MFMA(seq, Wb) + bcat ---------
// 256 threads (4 waves); 64 nodes x 128 outputs, K=128. A fragments loaded
// directly from global (4 lg-lanes cover 128 B contiguous per row); B staged
// once per block in LDS.
__global__ __launch_bounds__(256) void node_proj_kernel(
        const float* __restrict__ seq, const __hip_bfloat16* __restrict__ Wb,
        const float* __restrict__ bcat, _Float16* __restrict__ UVh, int nNodes)
{
    __shared__ short Bs[N_OUT * LDB];

    int tid  = threadIdx.x;
    int base = blockIdx.x * 64;

    // stage B: Wb [128][128] bf16 -> LDS (16B chunks, coalesced)
    #pragma unroll
    for (int it = 0; it < 8; ++it) {
        int c8 = tid + 256 * it;            // 8-elem chunk 0..2047
        int r  = c8 >> 4;                   // out row 0..127
        int cb = (c8 & 15) * 8;             // k 0..120
        *(int4*)(Bs + r * LDB + cb) = *(const int4*)(Wb + r * K_IN + cb);
    }
    __syncthreads();

    int lane = tid & 63;
    int w    = tid >> 6;       // wave 0..3 -> node rows [16w, 16w+16)
    int lr   = lane & 15;
    int lg   = lane >> 4;

    int arow = base + 16 * w + lr;
    if (arow >= nNodes) arow = nNodes - 1;
    const float* aptr = seq + (size_t)arow * K_IN + lg * 8;

    f32x4 acc[8];
    #pragma unroll
    for (int nt = 0; nt < 8; ++nt) {
        float b = bcat[nt * 16 + lr];
        acc[nt] = (f32x4){b, b, b, b};
    }

    #pragma unroll
    for (int kk = 0; kk < 4; ++kk) {
        float4 f0 = *(const float4*)(aptr + kk * 32);
        float4 f1 = *(const float4*)(aptr + kk * 32 + 4);
        bf16x8 a;
        a[0] = f2bf(f0.x); a[1] = f2bf(f0.y); a[2] = f2bf(f0.z); a[3] = f2bf(f0.w);
        a[4] = f2bf(f1.x); a[5] = f2bf(f1.y); a[6] = f2bf(f1.z); a[7] = f2bf(f1.w);
        #pragma unroll
        for (int nt = 0; nt < 8; ++nt) {
            bf16x8 b = *(bf16x8*)(Bs + (nt * 16 + lr) * LDB + kk * 32 + lg * 8);
            acc[nt] = __builtin_amdgcn_mfma_f32_16x16x32_bf16(a, b, acc[nt], 0, 0, 0);
        }
    }

    // store: D col = lane&15 (+16*nt), row = 4*lg + j  (m89/m91 mapping)
    int nodeb = base + 16 * w + lg * 4;
    #pragma unroll
    for (int j = 0; j < 4; ++j) {
        int node = nodeb + j;
        if (node < nNodes) {
            #pragma unroll
            for (int nt = 0; nt < 8; ++nt)
                UVh[(size_t)node * N_OUT + nt * 16 + lr] = (_Float16)acc[nt][j];
        }
    }
}

// ---------------- edge: 8 lanes/edge, x4 edge unroll for MLP --------------
__global__ __launch_bounds__(256) void edge_kernel(
        const _Float16* __restrict__ UVh, const int* __restrict__ row,
        const int* __restrict__ col, const float* __restrict__ W2,
        const float* __restrict__ b2, float* __restrict__ out, int nEdges)
{
    int l = threadIdx.x & 7;
    float w2v[8];
    #pragma unroll
    for (int j = 0; j < 8; ++j) w2v[j] = W2[l * 8 + j];
    float bb = b2[0];

    int gid = (int)((blockIdx.x * blockDim.x + threadIdx.x) >> 3);
    int ng  = (int)((gridDim.x * blockDim.x) >> 3);

    for (int e0 = gid * 4; e0 < nEdges; e0 += ng * 4) {
        if (e0 + 4 <= nEdges) {
            int4 r4 = *(const int4*)(row + e0);
            int4 c4 = *(const int4*)(col + e0);
            // issue all 8 gathers before any compute
            half8 a0 = *(const half8*)(UVh + (size_t)r4.x * N_OUT + l * 8);
            half8 b0 = *(const half8*)(UVh + (size_t)c4.x * N_OUT + 64 + l * 8);
            half8 a1 = *(const half8*)(UVh + (size_t)r4.y * N_OUT + l * 8);
            half8 b1 = *(const half8*)(UVh + (size_t)c4.y * N_OUT + 64 + l * 8);
            half8 a2 = *(const half8*)(UVh + (size_t)r4.z * N_OUT + l * 8);
            half8 b2v = *(const half8*)(UVh + (size_t)c4.z * N_OUT + 64 + l * 8);
            half8 a3 = *(const half8*)(UVh + (size_t)r4.w * N_OUT + l * 8);
            half8 b3 = *(const half8*)(UVh + (size_t)c4.w * N_OUT + 64 + l * 8);

            float p0 = 0.f, p1 = 0.f, p2 = 0.f, p3 = 0.f;
            #pragma unroll
            for (int j = 0; j < 8; ++j) {
                p0 = fmaf(fmaxf((float)a0[j] + (float)b0[j], 0.f), w2v[j], p0);
                p1 = fmaf(fmaxf((float)a1[j] + (float)b1[j], 0.f), w2v[j], p1);
                p2 = fmaf(fmaxf((float)a2[j] + (float)b2v[j], 0.f), w2v[j], p2);
                p3 = fmaf(fmaxf((float)a3[j] + (float)b3[j], 0.f), w2v[j], p3);
            }
            #pragma unroll
            for (int s = 1; s < 8; s <<= 1) {
                p0 += __shfl_xor(p0, s);
                p1 += __shfl_xor(p1, s);
                p2 += __shfl_xor(p2, s);
                p3 += __shfl_xor(p3, s);
            }
            if (l == 0)
                *(float4*)(out + e0) = make_float4(p0 + bb, p1 + bb, p2 + bb, p3 + bb);
        } else {
            for (int e = e0; e < nEdges; ++e) {
                int r = row[e];
                int c = col[e];
                half8 a = *(const half8*)(UVh + (size_t)r * N_OUT + l * 8);
                half8 b = *(const half8*)(UVh + (size_t)c * N_OUT + 64 + l * 8);
                float p = 0.f;
                #pragma unroll
                for (int j = 0; j < 8; ++j)
                    p = fmaf(fmaxf((float)a[j] + (float)b[j], 0.f), w2v[j], p);
                #pragma unroll
                for (int s = 1; s < 8; s <<= 1) p += __shfl_xor(p, s);
                if (l == 0) out[e] = p + bb;
            }
        }
    }
}

extern "C" void kernel_launch(void* const* d_in, const int* in_sizes, int n_in,
                              void* d_out, int out_size, void* d_ws, size_t ws_size,
                              hipStream_t stream) {
    const float* seq   = (const float*)d_in[0];
    const float* W_enc = (const float*)d_in[1];
    const float* b_enc = (const float*)d_in[2];
    const float* W1    = (const float*)d_in[3];
    const float* b1    = (const float*)d_in[4];
    const float* W2    = (const float*)d_in[5];
    const float* b2    = (const float*)d_in[6];
    const int*   row   = (const int*)d_in[7];
    const int*   col   = (const int*)d_in[8];
    float* out = (float*)d_out;

    int nNodes = in_sizes[0] / K_IN;     // 100000
    int nEdges = in_sizes[7];            // 1000000

    // workspace layout
    _Float16* UVh = (_Float16*)d_ws;                                   // 25.6 MB
    __hip_bfloat16* Wb = (__hip_bfloat16*)((char*)d_ws +
                         (size_t)nNodes * N_OUT * sizeof(_Float16));   // 32 KB
    float* bcat = (float*)((char*)Wb + N_OUT * K_IN * sizeof(__hip_bfloat16));

    prep_kernel<<<(N_OUT * K_IN + 255) / 256, 256, 0, stream>>>(
        W_enc, b_enc, W1, b1, Wb, bcat);

    int nblocksA = (nNodes + 63) / 64;
    node_proj_kernel<<<nblocksA, 256, 0, stream>>>(seq, Wb, bcat, UVh, nNodes);

    edge_kernel<<<2048, 256, 0, stream>>>(UVh, row, col, W2, b2, out, nEdges);
}